// Round 10
// baseline (488.626 us; speedup 1.0000x reference)
//
#include <hip/hip_runtime.h>

// ---- problem constants ----
#define TT   512
#define BI   12
#define HH   50
#define BB   4     // batch per block
#define BTOT 2048
#define LOG2E 1.4426950408889634f

// R10 = R9 (397 us: MFMA fp16, DPP merge, exp2 trans, compile-time parity)
// split into 2 independent blocks/CU: 512-thread blocks, BB=4, grid 512.
// R9's ledger: 850 cyc/SIMD-step VALU issue + ~750 cyc un-overlapped
// latency (single 16-wave barrier domain, 1 block/CU -> nothing fills the
// drain). R7 tested 2 blocks/CU but with two confounds (scratch-LDS merge
// round-trip + 2.2e7 bank conflicts) that R8's DPP merge removed; this is
// the clean test. 8 waves/block: wv>>2 = layer, wl = wv&3; wave wl owns
// M-tiles {wl, wl+4, wl+8, (wl+12 if <13)}. 4-slot merge: 3 DPP selects
// (row_ror:12/8/4, bank_mask 2/4/8) put tile s's batch cols (src n16<4)
// into dst lanes n16 = s*4+bcol -> one activation bundle per wave, trans
// bundles/CU unchanged (16). Everything else identical to R9.

typedef _Float16 half8 __attribute__((ext_vector_type(8)));
typedef float    f4    __attribute__((ext_vector_type(4)));

__device__ __forceinline__ float sigm_(float v) {
    return __builtin_amdgcn_rcpf(1.f + __builtin_amdgcn_exp2f(v * (-LOG2E)));
}
__device__ __forceinline__ float tanh_(float v) {
    return 1.f - 2.f * __builtin_amdgcn_rcpf(1.f + __builtin_amdgcn_exp2f(v * (2.f * LOG2E)));
}
// dst banks in BANK take src from lane (i+ror)&15 within the 16-lane row;
// other dst lanes keep `o`. One 2-cyc VALU op.
template <int CTRL, int BANK>
__device__ __forceinline__ float dppsel_(float o, float s) {
    int r = __builtin_amdgcn_update_dpp(__builtin_bit_cast(int, o),
                                        __builtin_bit_cast(int, s),
                                        CTRL, 0xF, BANK, false);
    return __builtin_bit_cast(float, r);
}

__launch_bounds__(512, 4)
__global__ void lstm2_kernel(const float* __restrict__ x,
                             const float* __restrict__ w_ih0, const float* __restrict__ w_hh0,
                             const float* __restrict__ b_ih0, const float* __restrict__ b_hh0,
                             const float* __restrict__ w_ih1, const float* __restrict__ w_hh1,
                             const float* __restrict__ b_ih1, const float* __restrict__ b_hh1,
                             const float* __restrict__ w_out, const float* __restrict__ b_out,
                             float* __restrict__ out)
{
    const int tid   = threadIdx.x;
    const int wv    = tid >> 6;          // 0..7
    const int lane  = tid & 63;
    const int layer = wv >> 2;           // 0 or 1
    const int wl    = wv & 3;            // wave within layer
    const int b0    = blockIdx.x * BB;
    const int ntile = (wl == 0) ? 4 : 3; // tiles wl, wl+4, wl+8 (, wl+12<13)

    __shared__ __align__(16) _Float16 B0s[2][64  * 16];
    __shared__ __align__(16) _Float16 B1s[2][128 * 16];

    // ---- step-invariant A fragments (weights, fragment layout) ----
    const int m = lane & 15;
    const int q = lane >> 4;
    half8 af[4][4];
    #pragma unroll
    for (int s = 0; s < 4; s++) {
        const int T = wl + 4 * s;
        #pragma unroll
        for (int kb = 0; kb < 4; kb++) {
            #pragma unroll
            for (int j = 0; j < 8; j++) {
                float v = 0.f;
                if (s < ntile && (layer == 1 || kb < 2)) {
                    const int u  = T * 4 + (m >> 2);
                    const int g  = m & 3;
                    const int kg = kb * 32 + q * 8 + j;
                    if (u < HH) {
                        const int r = g * HH + u;
                        if (layer == 0) {
                            if      (kg < 12)  v = w_ih0[r * BI + kg];
                            else if (kg < 62)  v = w_hh0[r * HH + (kg - 12)];
                            else if (kg == 62) v = b_ih0[r] + b_hh0[r];
                        } else {
                            if      (kg < 50)  v = w_ih1[r * HH + kg];
                            else if (kg < 64)  v = 0.f;
                            else if (kg < 114) v = w_hh1[r * HH + (kg - 64)];
                            else if (kg == 114) v = b_ih1[r] + b_hh1[r];
                        }
                    }
                }
                af[s][kb][j] = (_Float16)v;
            }
        }
    }

    // ---- init LDS ----
    for (int i = tid; i < 2 * 64 * 16;  i += 512) (&B0s[0][0])[i] = (_Float16)0.f;
    for (int i = tid; i < 2 * 128 * 16; i += 512) (&B1s[0][0])[i] = (_Float16)0.f;
    __syncthreads();
    if (tid < 16) {                       // bias (ones) rows, both parities
        B0s[0][7  * 128 + tid * 8 + 6] = (_Float16)1.f;
        B0s[1][7  * 128 + tid * 8 + 6] = (_Float16)1.f;
        B1s[0][14 * 128 + tid * 8 + 2] = (_Float16)1.f;
        B1s[1][14 * 128 + tid * 8 + 2] = (_Float16)1.f;
    }
    const int xb = tid / 12, xi = tid - xb * 12;           // tid<48 roles
    const int xoff = (xi >> 3) * 128 + xb * 8 + (xi & 7);
    const size_t xbase = ((size_t)(b0 + xb) * TT) * BI + xi;
    if (tid < 48)                          // x[0] -> parity 0
        B0s[0][xoff] = (_Float16)x[xbase];
    __syncthreads();

    // ---- merged update role: lane owns (u_m, bcol) via 4-slot DPP merge ----
    const int n16  = lane & 15;
    const int slot = n16 >> 2;            // which of this wave's 4 tiles
    const int bcol = n16 & 3;             // batch column
    const int Ts   = wl + 4 * slot;
    const int u_m  = Ts * 4 + q;
    const bool wvalid = (Ts <= 12) && (u_m < HH);
    float cm = 0.f;                        // cell state for (u_m, bcol)

    // ---- per-parity pointers (constant-indexed -> folded) ----
    const _Float16* rdA[2] = { (layer ? &B1s[0][0] : &B0s[0][0]) + lane * 8,
                               (layer ? &B1s[1][0] : &B0s[1][0]) + lane * 8 };
    const int k0 = 12 + u_m;              // h0 row in B0
    const int k1 = 64 + u_m;              // h1 row in B1
    const int offA = layer ? ((k1 >> 3) * 128 + bcol * 8 + (k1 & 7))
                           : ((k0 >> 3) * 128 + bcol * 8 + (k0 & 7));
    const int offB = (u_m >> 3) * 128 + bcol * 8 + (u_m & 7);   // h0 row in B1
    _Float16* wAp[2] = { (layer ? &B1s[0][0] : &B0s[0][0]) + offA,
                         (layer ? &B1s[1][0] : &B0s[1][0]) + offA };
    _Float16* wBp[2] = { &B1s[0][0] + offB, &B1s[1][0] + offB };
    _Float16* xdp[2] = { &B0s[0][0] + xoff, &B0s[1][0] + xoff };

    const float* xq = x + xbase + BI;     // x[t+1] stream (lanes tid<48)

// One timestep at compile-time parity P. DOL0/DOL1: layer activity at the
// peeled boundaries. DOX: prefetch x[t+1] into parity 1-P.
#define STEP(P, DOL0, DOL1, DOX)                                              \
  {                                                                           \
    float xpre = 0.f;                                                         \
    if ((DOX) && tid < 48) xpre = *xq;                                        \
    if ((layer == 0) ? (DOL0) : (DOL1)) {                                     \
      f4 acc[4];                                                              \
      _Pragma("unroll")                                                       \
      for (int s = 0; s < 4; s++) acc[s] = (f4){0.f, 0.f, 0.f, 0.f};          \
      const _Float16* Bp = rdA[P];                                            \
      if (layer == 0) {                                                       \
        _Pragma("unroll")                                                     \
        for (int kb = 0; kb < 2; kb++) {                                      \
          const half8 bf = *(const half8*)(Bp + kb * 512);                    \
          _Pragma("unroll")                                                   \
          for (int s = 0; s < 4; s++)                                         \
            if (s < ntile)                                                    \
              acc[s] = __builtin_amdgcn_mfma_f32_16x16x32_f16(af[s][kb], bf, acc[s], 0, 0, 0); \
        }                                                                     \
      } else {                                                                \
        _Pragma("unroll")                                                     \
        for (int kb = 0; kb < 4; kb++) {                                      \
          const half8 bf = *(const half8*)(Bp + kb * 512);                    \
          _Pragma("unroll")                                                   \
          for (int s = 0; s < 4; s++)                                         \
            if (s < ntile)                                                    \
              acc[s] = __builtin_amdgcn_mfma_f32_16x16x32_f16(af[s][kb], bf, acc[s], 0, 0, 0); \
        }                                                                     \
      }                                                                       \
      f4 am;                                                                  \
      _Pragma("unroll")                                                       \
      for (int i = 0; i < 4; i++) {                                           \
        float t1 = dppsel_<0x12C, 0x2>(acc[0][i], acc[1][i]);                 \
        float t2 = dppsel_<0x128, 0x4>(t1, acc[2][i]);                        \
        am[i]    = dppsel_<0x124, 0x8>(t2, acc[3][i]);                        \
      }                                                                       \
      const float iv = sigm_(am[0]);                                          \
      const float fv = sigm_(am[1]);                                          \
      const float gv = tanh_(am[2]);                                          \
      const float ov = sigm_(am[3]);                                          \
      cm = fv * cm + iv * gv;                                                 \
      const float h = ov * tanh_(cm);                                         \
      if (wvalid) {                                                           \
        const _Float16 hh = (_Float16)h;                                      \
        *wAp[1 - (P)] = hh;                                                   \
        if (layer == 0) *wBp[1 - (P)] = hh;                                   \
      }                                                                       \
    }                                                                         \
    if ((DOX) && tid < 48) *xdp[1 - (P)] = (_Float16)xpre;                    \
    if (DOX) xq += BI;                                                        \
    __syncthreads();                                                          \
  }

    STEP(0, 1, 0, 1)                      // t = 0   (l0 only)
    STEP(1, 1, 1, 1)                      // t = 1
    #pragma unroll 1
    for (int it = 0; it < 254; ++it) {    // t = 2 .. 509
        STEP(0, 1, 1, 1)
        STEP(1, 1, 1, 1)
    }
    STEP(0, 1, 1, 1)                      // t = 510 (prefetch x[511])
    STEP(1, 1, 1, 0)                      // t = 511 (no prefetch)
    STEP(0, 0, 1, 0)                      // t = 512 (l1 only)
#undef STEP

    // ---- epilogue: sigmoid(h1[TT-1] . w_out + b_out); h1[TT-1] in parity 1 ----
    if (tid < BB) {
        float s = b_out[0];
        #pragma unroll
        for (int u = 0; u < HH; u++) {
            const int kk = 64 + u;
            s += w_out[u] * (float)B1s[1][(kk >> 3) * 128 + tid * 8 + (kk & 7)];
        }
        out[b0 + tid] = sigm_(s);
    }
}

extern "C" void kernel_launch(void* const* d_in, const int* in_sizes, int n_in,
                              void* d_out, int out_size, void* d_ws, size_t ws_size,
                              hipStream_t stream) {
    const float* x     = (const float*)d_in[0];
    const float* w_ih0 = (const float*)d_in[1];
    const float* w_hh0 = (const float*)d_in[2];
    const float* b_ih0 = (const float*)d_in[3];
    const float* b_hh0 = (const float*)d_in[4];
    const float* w_ih1 = (const float*)d_in[5];
    const float* w_hh1 = (const float*)d_in[6];
    const float* b_ih1 = (const float*)d_in[7];
    const float* b_hh1 = (const float*)d_in[8];
    const float* w_out = (const float*)d_in[9];
    const float* b_out = (const float*)d_in[10];
    float* out = (float*)d_out;

    dim3 grid(BTOT / BB);   // 512 blocks -> 2 per CU (independent barriers)
    dim3 block(512);        // 8 waves: 4 layer-0 + 4 layer-1
    lstm2_kernel<<<grid, block, 0, stream>>>(x, w_ih0, w_hh0, b_ih0, b_hh0,
                                             w_ih1, w_hh1, b_ih1, b_hh1,
                                             w_out, b_out, out);
}